// Round 1
// baseline (461.567 us; speedup 1.0000x reference)
//
#include <hip/hip_runtime.h>

typedef unsigned short u16;
typedef __attribute__((ext_vector_type(4))) unsigned short u16x4;
typedef __attribute__((ext_vector_type(8))) __bf16 bf16x8;
typedef __attribute__((ext_vector_type(4))) float f32x4;

#define B_ 16
#define T_ 128
#define N_ 64
#define CI 128
#define CO 256

__device__ __forceinline__ u16 f2b(float f) {
    unsigned x = __builtin_bit_cast(unsigned, f);
    x += 0x7fffu + ((x >> 16) & 1u);
    return (u16)(x >> 16);
}
__device__ __forceinline__ float b2f(u16 u) {
    unsigned x = ((unsigned)u) << 16;
    return __builtin_bit_cast(float, x);
}

// ---------------- prep: M[n,o,c] = sum_k s[k,n]*dw[k,c]*Wpw[o,k*128+c]  (bf16) ----------------
__global__ void prep_kernel(const float* __restrict__ A, const float* __restrict__ dw,
                            const float* __restrict__ Wpw, const float* __restrict__ Wres,
                            u16* __restrict__ Mg, u16* __restrict__ WresB) {
    int n = blockIdx.x;
    int tid = threadIdx.x;
    float s0 = 0.f, s1 = 0.f, s2 = 0.f;
    for (int m = 0; m < N_; ++m) {
        s0 += A[(0 * N_ + n) * N_ + m];
        s1 += A[(1 * N_ + n) * N_ + m];
        s2 += A[(2 * N_ + n) * N_ + m];
    }
    for (int j = 0; j < (CO * CI) / 256; ++j) {
        int idx = tid + j * 256;
        int o = idx >> 7, c = idx & (CI - 1);
        float v = s0 * dw[c]          * Wpw[o * (3 * CI) + c]
                + s1 * dw[CI + c]     * Wpw[o * (3 * CI) + CI + c]
                + s2 * dw[2 * CI + c] * Wpw[o * (3 * CI) + 2 * CI + c];
        Mg[((size_t)n << 15) + idx] = f2b(v);
    }
    if (n == 0) {
        for (int j = 0; j < (CO * CI) / 256; ++j) {
            int idx = tid + j * 256;
            WresB[idx] = f2b(Wres[idx]);
        }
    }
}

// ---------------- fused: GEMM (h, r) + conv + GN + LN + GELU, one block per (b,n) ----------------
__global__ __launch_bounds__(512, 2) void fused_kernel(
    const float* __restrict__ xg, const u16* __restrict__ Mg, const u16* __restrict__ WresB,
    const float* __restrict__ Wconv, const float* __restrict__ gnw, const float* __restrict__ gnb,
    const float* __restrict__ lnw, const float* __restrict__ lnb, float* __restrict__ out)
{
    __shared__ __align__(16) u16 hs[T_ * CO];   // 64KB h slab; first 32KB doubles as x-frag buffer
    __shared__ __align__(16) u16 rs[T_ * CO];   // 64KB residual slab
    __shared__ float gpart[16][2];
    __shared__ float gmean[8], grstd[8];
    __shared__ float lnpart[T_][4][2];

    const int tid = threadIdx.x;
    const int bid = blockIdx.x;
    const int n = bid & 63, b = bid >> 6;       // same-n blocks stride 64 => same XCD (L2 reuse of M[n])

    u16* xf = hs;                                // x fragment region (32KB), dead before hs is written
    const float* xb = xg + (((size_t)b * T_) * N_ + n) * CI;

    // ---- stage x[b,:,n,:] (128x128 f32) -> bf16, pre-swizzled into A-fragment order ----
#pragma unroll
    for (int it = 0; it < 8; ++it) {
        int f = tid + (it << 9);                 // 0..4095 float4s
        int t = f >> 5;
        int c4 = (f & 31) << 2;                  // 0,4,...,124
        float4 v = *(const float4*)(xb + (size_t)t * (N_ * CI) + c4);
        int kkk = c4 >> 5, quad = (c4 >> 3) & 3, j = c4 & 7;
        int mt = t >> 4;
        int sl = quad * 16 + (t & 15);
        int off = ((kkk * 8 + mt) << 9) + (sl << 3) + j;   // ushort units
        u16x4 u = { f2b(v.x), f2b(v.y), f2b(v.z), f2b(v.w) };
        *(u16x4*)(xf + off) = u;
    }
    __syncthreads();

    // ---- GEMM: h[t,o] = x . M[n]^T ; r[t,o] = x . Wres^T  (MFMA 16x16x32 bf16) ----
    const int wid = tid >> 6, lane = tid & 63;
    const int wt = wid >> 2, wo = wid & 3;       // wave tile: t in [wt*64,+64), o in [wo*64,+64)
    const int lr = lane & 15, lq = lane >> 4;
    f32x4 ah[4][4], ar[4][4];
#pragma unroll
    for (int mi = 0; mi < 4; ++mi)
#pragma unroll
        for (int ni = 0; ni < 4; ++ni) {
            ah[mi][ni] = (f32x4){0.f, 0.f, 0.f, 0.f};
            ar[mi][ni] = (f32x4){0.f, 0.f, 0.f, 0.f};
        }
    const u16* Mn = Mg + ((size_t)n << 15);
#pragma unroll
    for (int kk = 0; kk < 4; ++kk) {
        bf16x8 af[4];
#pragma unroll
        for (int mi = 0; mi < 4; ++mi)
            af[mi] = *(const bf16x8*)(xf + ((kk * 8 + wt * 4 + mi) << 9) + (lane << 3));
        const int c = kk * 32 + lq * 8;
#pragma unroll
        for (int ni = 0; ni < 4; ++ni) {
            const int o = wo * 64 + ni * 16 + lr;
            bf16x8 bm = *(const bf16x8*)(Mn + o * CI + c);
            bf16x8 br = *(const bf16x8*)(WresB + o * CI + c);
#pragma unroll
            for (int mi = 0; mi < 4; ++mi) {
                ah[mi][ni] = __builtin_amdgcn_mfma_f32_16x16x32_bf16(af[mi], bm, ah[mi][ni], 0, 0, 0);
                ar[mi][ni] = __builtin_amdgcn_mfma_f32_16x16x32_bf16(af[mi], br, ar[mi][ni], 0, 0, 0);
            }
        }
    }
    __syncthreads();   // all waves done reading xf => safe to overwrite with h

    // ---- spill h, r to LDS (bf16). C/D layout: col=lane&15, row=(lane>>4)*4+e ----
#pragma unroll
    for (int mi = 0; mi < 4; ++mi)
#pragma unroll
        for (int ni = 0; ni < 4; ++ni) {
            int o = wo * 64 + ni * 16 + lr;
#pragma unroll
            for (int e = 0; e < 4; ++e) {
                int t = wt * 64 + mi * 16 + lq * 4 + e;
                hs[t * CO + o] = f2b(ah[mi][ni][e]);
                rs[t * CO + o] = f2b(ar[mi][ni][e]);
            }
        }
    __syncthreads();

    // ---- epilogue mapping: thread -> (channel o, T-half th) ----
    const int o = tid & 255, th = tid >> 8;
    const int g = o >> 5;
    const float w0 = Wconv[o * 3 + 0], w1 = Wconv[o * 3 + 1], w2 = Wconv[o * 3 + 2];

    // phase 1: GroupNorm stats of conv output (per (b,n,group), 32ch x 128T)
    float sum = 0.f, ssq = 0.f;
    for (int i = 0; i < 64; ++i) {
        int t = th * 64 + i;
        float hm = (t > 0)      ? b2f(hs[(t - 1) * CO + o]) : 0.f;
        float hp = (t < T_ - 1) ? b2f(hs[(t + 1) * CO + o]) : 0.f;
        float hc = w0 * hm + w1 * b2f(hs[t * CO + o]) + w2 * hp;
        sum += hc; ssq += hc * hc;
    }
#pragma unroll
    for (int m = 1; m < 32; m <<= 1) {           // 32 lanes of a half-wave = one group
        sum += __shfl_xor(sum, m);
        ssq += __shfl_xor(ssq, m);
    }
    if ((tid & 31) == 0) { gpart[tid >> 5][0] = sum; gpart[tid >> 5][1] = ssq; }
    __syncthreads();
    if (tid < 8) {
        float s = gpart[tid][0] + gpart[tid + 8][0];
        float q = gpart[tid][1] + gpart[tid + 8][1];
        float mu = s * (1.f / 4096.f);
        float var = q * (1.f / 4096.f) - mu * mu;
        gmean[tid] = mu;
        grstd[tid] = rsqrtf(var + 1e-5f);
    }
    __syncthreads();

    const float mg = gmean[g], rg = grstd[g];
    const float gwm = gnw[o] * rg;
    const float gbm = gnb[o] - mg * gwm;
    const int wo4 = (tid >> 6) & 3;

    // phase 2A: LayerNorm partials per t (each wave covers 64 consecutive channels)
    for (int i = 0; i < 64; ++i) {
        int t = th * 64 + i;
        float hm = (t > 0)      ? b2f(hs[(t - 1) * CO + o]) : 0.f;
        float hp = (t < T_ - 1) ? b2f(hs[(t + 1) * CO + o]) : 0.f;
        float hc = w0 * hm + w1 * b2f(hs[t * CO + o]) + w2 * hp;
        float v = hc * gwm + gbm + b2f(rs[t * CO + o]);
        float s = v, q = v * v;
#pragma unroll
        for (int m = 1; m < 64; m <<= 1) {
            s += __shfl_xor(s, m);
            q += __shfl_xor(q, m);
        }
        if (lane == 0) { lnpart[t][wo4][0] = s; lnpart[t][wo4][1] = q; }
    }
    __syncthreads();

    // phase 2B: finalize LN + GELU, coalesced stores
    const float lw = lnw[o], lb = lnb[o];
    for (int i = 0; i < 64; ++i) {
        int t = th * 64 + i;
        float s = lnpart[t][0][0] + lnpart[t][1][0] + lnpart[t][2][0] + lnpart[t][3][0];
        float q = lnpart[t][0][1] + lnpart[t][1][1] + lnpart[t][2][1] + lnpart[t][3][1];
        float mu = s * (1.f / 256.f);
        float var = q * (1.f / 256.f) - mu * mu;
        float rstd = rsqrtf(var + 1e-5f);
        float hm = (t > 0)      ? b2f(hs[(t - 1) * CO + o]) : 0.f;
        float hp = (t < T_ - 1) ? b2f(hs[(t + 1) * CO + o]) : 0.f;
        float hc = w0 * hm + w1 * b2f(hs[t * CO + o]) + w2 * hp;
        float v = hc * gwm + gbm + b2f(rs[t * CO + o]);
        float u = (v - mu) * rstd * lw + lb;
        float ge = 0.5f * u * (1.f + erff(u * 0.70710678118654752f));
        out[(((size_t)b * T_ + t) * N_ + n) * CO + o] = ge;
    }
}

extern "C" void kernel_launch(void* const* d_in, const int* in_sizes, int n_in,
                              void* d_out, int out_size, void* d_ws, size_t ws_size,
                              hipStream_t stream) {
    const float* x    = (const float*)d_in[0];
    const float* A    = (const float*)d_in[1];
    const float* dw   = (const float*)d_in[2];
    const float* Wpw  = (const float*)d_in[3];
    const float* Wcv  = (const float*)d_in[4];
    const float* gnw  = (const float*)d_in[5];
    const float* gnb  = (const float*)d_in[6];
    const float* lnw  = (const float*)d_in[7];
    const float* lnb  = (const float*)d_in[8];
    const float* Wres = (const float*)d_in[9];

    u16* Mg    = (u16*)d_ws;                          // 64*256*128 bf16 = 4MB
    u16* WresB = Mg + (size_t)N_ * CO * CI;           // 256*128 bf16 = 64KB

    prep_kernel<<<N_, 256, 0, stream>>>(A, dw, Wpw, Wres, Mg, WresB);
    fused_kernel<<<B_ * N_, 512, 0, stream>>>(x, Mg, WresB, Wcv, gnw, gnb, lnw, lnb, (float*)d_out);
}

// Round 2
// 286.266 us; speedup vs baseline: 1.6124x; 1.6124x over previous
//
#include <hip/hip_runtime.h>

typedef unsigned short u16;
typedef __attribute__((ext_vector_type(4))) unsigned short u16x4;
typedef __attribute__((ext_vector_type(8))) __bf16 bf16x8;
typedef __attribute__((ext_vector_type(4))) float f32x4;

#define B_ 16
#define T_ 128
#define N_ 64
#define CI 128
#define CO 256

__device__ __forceinline__ u16 f2b(float f) {
    unsigned x = __builtin_bit_cast(unsigned, f);
    x += 0x7fffu + ((x >> 16) & 1u);
    return (u16)(x >> 16);
}

// ---------------- prep: M[n,o,c] = sum_k s[k,n]*dw[k,c]*Wpw[o,k*128+c]  (bf16) ----------------
// grid: 256 blocks = (n, o-chunk of 64), 256 threads
__global__ void prep_kernel(const float* __restrict__ A, const float* __restrict__ dw,
                            const float* __restrict__ Wpw, const float* __restrict__ Wres,
                            u16* __restrict__ Mg, u16* __restrict__ WresB) {
    int n = blockIdx.x >> 2, ch = blockIdx.x & 3;
    int tid = threadIdx.x;
    float s0 = 0.f, s1 = 0.f, s2 = 0.f;
    for (int m = 0; m < N_; ++m) {           // A rows are wave-uniform (scalar loads, L2-hot)
        s0 += A[(0 * N_ + n) * N_ + m];
        s1 += A[(1 * N_ + n) * N_ + m];
        s2 += A[(2 * N_ + n) * N_ + m];
    }
#pragma unroll
    for (int i = 0; i < 8; ++i) {
        int e4 = tid + i * 256;              // 2048 float4-groups per chunk
        int ol = e4 >> 5, c4 = (e4 & 31) << 2;
        int o = ch * 64 + ol;
        float4 d0 = *(const float4*)(dw + c4);
        float4 d1 = *(const float4*)(dw + CI + c4);
        float4 d2 = *(const float4*)(dw + 2 * CI + c4);
        float4 p0 = *(const float4*)(Wpw + (size_t)o * 3 * CI + c4);
        float4 p1 = *(const float4*)(Wpw + (size_t)o * 3 * CI + CI + c4);
        float4 p2 = *(const float4*)(Wpw + (size_t)o * 3 * CI + 2 * CI + c4);
        u16x4 u = { f2b(s0 * d0.x * p0.x + s1 * d1.x * p1.x + s2 * d2.x * p2.x),
                    f2b(s0 * d0.y * p0.y + s1 * d1.y * p1.y + s2 * d2.y * p2.y),
                    f2b(s0 * d0.z * p0.z + s1 * d1.z * p1.z + s2 * d2.z * p2.z),
                    f2b(s0 * d0.w * p0.w + s1 * d1.w * p1.w + s2 * d2.w * p2.w) };
        *(u16x4*)(Mg + ((size_t)n << 15) + o * CI + c4) = u;
        if (n == 0) {
            float4 r = *(const float4*)(Wres + (size_t)o * CI + c4);
            u16x4 ur = { f2b(r.x), f2b(r.y), f2b(r.z), f2b(r.w) };
            *(u16x4*)(WresB + o * CI + c4) = ur;
        }
    }
}

// ---------------- fused: GEMM + in-register conv/GN/LN/GELU, one block per (b,n) ----------------
__global__ __launch_bounds__(512, 2) void fused_kernel(
    const float* __restrict__ xg, const u16* __restrict__ Mg, const u16* __restrict__ WresB,
    const float* __restrict__ Wconv, const float* __restrict__ gnw, const float* __restrict__ gnb,
    const float* __restrict__ lnw, const float* __restrict__ lnb, float* __restrict__ out)
{
    __shared__ __align__(16) u16 xf[T_ * CI];     // 32 KB x in A-fragment order
    __shared__ float ebA[CO], ebB[CO];            // conv boundary rows h[63], h[64]
    __shared__ float gpart[8][2][2];              // [wave][group-half][s,q]
    __shared__ float gstat[8][2];                 // [group][mean,rstd]
    __shared__ float lnp[T_][10];                 // padded LN partials: wo -> slots 2wo, 2wo+1
    __shared__ float lnstat[T_][2];               // [t][mu,rstd]

    const int tid = threadIdx.x;
    const int bid = blockIdx.x;
    const int n = bid & 63, b = bid >> 6;         // same-n blocks share M[n] in L2
    const float* xb = xg + (((size_t)b * T_) * N_ + n) * CI;

    // ---- stage x[b,:,n,:] -> bf16 A-fragment order ----
#pragma unroll
    for (int it = 0; it < 8; ++it) {
        int f = tid + (it << 9);
        int t = f >> 5;
        int c4 = (f & 31) << 2;
        float4 v = *(const float4*)(xb + (size_t)t * (N_ * CI) + c4);
        int kkk = c4 >> 5, quad = (c4 >> 3) & 3, j = c4 & 7;
        int mt = t >> 4;
        int sl = quad * 16 + (t & 15);
        int off = ((kkk * 8 + mt) << 9) + (sl << 3) + j;
        u16x4 u = { f2b(v.x), f2b(v.y), f2b(v.z), f2b(v.w) };
        *(u16x4*)(xf + off) = u;
    }
    __syncthreads();

    const int wid = tid >> 6, lane = tid & 63;
    const int wt = wid >> 2, wo = wid & 3;        // wave tile: t in [wt*64,+64), o in [wo*64,+64)
    const int lr = lane & 15, lq = lane >> 4;

    // ---- GEMM: ah = x.M[n]^T, ar = x.Wres^T ----
    f32x4 ah[4][4], ar[4][4];
#pragma unroll
    for (int mi = 0; mi < 4; ++mi)
#pragma unroll
        for (int ni = 0; ni < 4; ++ni) {
            ah[mi][ni] = (f32x4){0.f, 0.f, 0.f, 0.f};
            ar[mi][ni] = (f32x4){0.f, 0.f, 0.f, 0.f};
        }
    const u16* Mn = Mg + ((size_t)n << 15);
#pragma unroll
    for (int kk = 0; kk < 4; ++kk) {
        bf16x8 af[4];
#pragma unroll
        for (int mi = 0; mi < 4; ++mi)
            af[mi] = *(const bf16x8*)(xf + ((kk * 8 + wt * 4 + mi) << 9) + (lane << 3));
        const int c = kk * 32 + lq * 8;
#pragma unroll
        for (int ni = 0; ni < 4; ++ni) {
            const int o = wo * 64 + ni * 16 + lr;
            bf16x8 bm = *(const bf16x8*)(Mn + o * CI + c);
            bf16x8 br = *(const bf16x8*)(WresB + o * CI + c);
#pragma unroll
            for (int mi = 0; mi < 4; ++mi) {
                ah[mi][ni] = __builtin_amdgcn_mfma_f32_16x16x32_bf16(af[mi], bm, ah[mi][ni], 0, 0, 0);
                ar[mi][ni] = __builtin_amdgcn_mfma_f32_16x16x32_bf16(af[mi], br, ar[mi][ni], 0, 0, 0);
            }
        }
    }

    // ---- exchange conv boundary rows (pre-conv h at t=63 / t=64) ----
    if (wt == 0 && lq == 3) {
#pragma unroll
        for (int ni = 0; ni < 4; ++ni) ebA[wo * 64 + ni * 16 + lr] = ah[3][ni][3];
    }
    if (wt == 1 && lq == 0) {
#pragma unroll
        for (int ni = 0; ni < 4; ++ni) ebB[wo * 64 + ni * 16 + lr] = ah[0][ni][0];
    }
    __syncthreads();

    // ---- per-lane channel params (tiny tables, L2-hot) ----
    float w0[4], w1[4], w2[4];
#pragma unroll
    for (int ni = 0; ni < 4; ++ni) {
        int o = wo * 64 + ni * 16 + lr;
        w0[ni] = Wconv[o * 3 + 0];
        w1[ni] = Wconv[o * 3 + 1];
        w2[ni] = Wconv[o * 3 + 2];
    }

    // ---- depthwise conv over t IN REGISTERS (overwrite ah with hc) + GN partials ----
    float gs0 = 0.f, gq0 = 0.f, gs1 = 0.f, gq1 = 0.f;
#pragma unroll
    for (int ni = 0; ni < 4; ++ni) {
        int o = wo * 64 + ni * 16 + lr;
        float up3[4], dn0[4];
#pragma unroll
        for (int mi = 0; mi < 4; ++mi) up3[mi] = __shfl(ah[mi][ni][3], (lane + 48) & 63);
#pragma unroll
        for (int mi = 0; mi < 4; ++mi) dn0[mi] = __shfl(ah[mi][ni][0], (lane + 16) & 63);
        float epv = ebA[o], env = ebB[o];
        float sA = 0.f, qA = 0.f;
#pragma unroll
        for (int mi = 0; mi < 4; ++mi) {
            float prev = (lq == 0) ? ((mi == 0) ? ((wt == 1) ? epv : 0.f) : up3[mi - 1]) : up3[mi];
            float nxt3 = (lq == 3) ? ((mi == 3) ? ((wt == 0) ? env : 0.f) : dn0[mi + 1]) : dn0[mi];
            float hm1 = prev;
#pragma unroll
            for (int e = 0; e < 4; ++e) {
                float cur = ah[mi][ni][e];
                float nx = (e < 3) ? ah[mi][ni][e + 1] : nxt3;
                float hc = w0[ni] * hm1 + w1[ni] * cur + w2[ni] * nx;
                hm1 = cur;
                ah[mi][ni][e] = hc;
                sA += hc;
                qA += hc * hc;
            }
        }
        if ((ni >> 1) == 0) { gs0 += sA; gq0 += qA; } else { gs1 += sA; gq1 += qA; }
    }
    // wave-reduce GN partials (each wave covers 2 groups x its t-half)
#pragma unroll
    for (int m = 1; m < 64; m <<= 1) {
        gs0 += __shfl_xor(gs0, m); gq0 += __shfl_xor(gq0, m);
        gs1 += __shfl_xor(gs1, m); gq1 += __shfl_xor(gq1, m);
    }
    if (lane == 0) {
        gpart[wid][0][0] = gs0; gpart[wid][0][1] = gq0;
        gpart[wid][1][0] = gs1; gpart[wid][1][1] = gq1;
    }
    __syncthreads();
    if (tid < 8) {                                 // group g: waves {g>>1, (g>>1)+4}, slot g&1
        float s = gpart[tid >> 1][tid & 1][0] + gpart[(tid >> 1) + 4][tid & 1][0];
        float q = gpart[tid >> 1][tid & 1][1] + gpart[(tid >> 1) + 4][tid & 1][1];
        float mu = s * (1.f / 4096.f);
        float var = q * (1.f / 4096.f) - mu * mu;
        gstat[tid][0] = mu;
        gstat[tid][1] = rsqrtf(var + 1e-5f);
    }
    __syncthreads();

    // ---- v = hc*gn + residual (in registers), LN per-t partials ----
    float lw[4], lb[4];
    float st[4][4], qt[4][4];
#pragma unroll
    for (int mi = 0; mi < 4; ++mi)
#pragma unroll
        for (int e = 0; e < 4; ++e) { st[mi][e] = 0.f; qt[mi][e] = 0.f; }
#pragma unroll
    for (int ni = 0; ni < 4; ++ni) {
        int o = wo * 64 + ni * 16 + lr;
        lw[ni] = lnw[o]; lb[ni] = lnb[o];
        float mg = gstat[wo * 2 + (ni >> 1)][0];
        float rg = gstat[wo * 2 + (ni >> 1)][1];
        float gwm = gnw[o] * rg;
        float gbm = gnb[o] - mg * gwm;
#pragma unroll
        for (int mi = 0; mi < 4; ++mi)
#pragma unroll
            for (int e = 0; e < 4; ++e) {
                float v = ah[mi][ni][e] * gwm + gbm + ar[mi][ni][e];
                ah[mi][ni][e] = v;
                st[mi][e] += v;
                qt[mi][e] += v * v;
            }
    }
    // reduce over lr (16 lanes, DPP xor 1,2,4,8); every lane of a row gets the row sum
#pragma unroll
    for (int m = 1; m < 16; m <<= 1)
#pragma unroll
        for (int mi = 0; mi < 4; ++mi)
#pragma unroll
            for (int e = 0; e < 4; ++e) {
                st[mi][e] += __shfl_xor(st[mi][e], m);
                qt[mi][e] += __shfl_xor(qt[mi][e], m);
            }
    if (lr == 0) {
#pragma unroll
        for (int mi = 0; mi < 4; ++mi)
#pragma unroll
            for (int e = 0; e < 4; ++e) {
                int t = wt * 64 + mi * 16 + lq * 4 + e;
                lnp[t][wo * 2] = st[mi][e];
                lnp[t][wo * 2 + 1] = qt[mi][e];
            }
    }
    __syncthreads();
    if (tid < T_) {
        float s = lnp[tid][0] + lnp[tid][2] + lnp[tid][4] + lnp[tid][6];
        float q = lnp[tid][1] + lnp[tid][3] + lnp[tid][5] + lnp[tid][7];
        float mu = s * (1.f / 256.f);
        float var = q * (1.f / 256.f) - mu * mu;
        lnstat[tid][0] = mu;
        lnstat[tid][1] = rsqrtf(var + 1e-5f);
    }
    __syncthreads();

    // ---- finalize: LN + exact GELU + store ----
    float* ob = out + (((size_t)b * T_ + wt * 64) * N_ + n) * CO + wo * 64;
#pragma unroll
    for (int mi = 0; mi < 4; ++mi)
#pragma unroll
        for (int e = 0; e < 4; ++e) {
            int tl = mi * 16 + lq * 4 + e;
            float mu = lnstat[wt * 64 + tl][0];
            float rs = lnstat[wt * 64 + tl][1];
#pragma unroll
            for (int ni = 0; ni < 4; ++ni) {
                float u = (ah[mi][ni][e] - mu) * rs * lw[ni] + lb[ni];
                float ge = 0.5f * u * (1.f + erff(u * 0.70710678118654752f));
                ob[(size_t)tl * (N_ * CO) + ni * 16 + lr] = ge;
            }
        }
}

extern "C" void kernel_launch(void* const* d_in, const int* in_sizes, int n_in,
                              void* d_out, int out_size, void* d_ws, size_t ws_size,
                              hipStream_t stream) {
    const float* x    = (const float*)d_in[0];
    const float* A    = (const float*)d_in[1];
    const float* dw   = (const float*)d_in[2];
    const float* Wpw  = (const float*)d_in[3];
    const float* Wcv  = (const float*)d_in[4];
    const float* gnw  = (const float*)d_in[5];
    const float* gnb  = (const float*)d_in[6];
    const float* lnw  = (const float*)d_in[7];
    const float* lnb  = (const float*)d_in[8];
    const float* Wres = (const float*)d_in[9];

    u16* Mg    = (u16*)d_ws;                          // 64*256*128 bf16 = 4MB
    u16* WresB = Mg + (size_t)N_ * CO * CI;           // 256*128 bf16 = 64KB

    prep_kernel<<<N_ * 4, 256, 0, stream>>>(A, dw, Wpw, Wres, Mg, WresB);
    fused_kernel<<<B_ * N_, 512, 0, stream>>>(x, Mg, WresB, Wcv, gnw, gnb, lnw, lnb, (float*)d_out);
}